// Round 16
// baseline (114.321 us; speedup 1.0000x reference)
//
#include <hip/hip_runtime.h>
#include <math.h>

#define B_  2
#define T_  2048
#define C_  1024
#define H_  16
#define HD_ 64
#define F3_ 3072   // 3*C

// float4 unit counts for cvt_all (derived, not hand-copied):
#define X4_   ((B_ * T_ * C_) / 4)         // 2*2048*1024/4 = 1,048,576
#define WA4_  ((F3_ * C_) / 4)             // 3072*1024/4   =   786,432
#define WP4_  ((C_ * C_) / 4)              // 1024*1024/4   =   262,144
#define TOT4_ (X4_ + WA4_ + WP4_)          //               = 2,097,152 = 8192*256

typedef __attribute__((ext_vector_type(8))) __bf16 bf16x8;
typedef __attribute__((ext_vector_type(4))) float  f32x4;

__device__ __forceinline__ ushort f2bf(float f) {
  uint32_t u = __builtin_bit_cast(uint32_t, f);
  u += 0x7fff + ((u >> 16) & 1);        // RNE
  return (ushort)(u >> 16);
}
__device__ __forceinline__ float bf2f(ushort u) {
  return __builtin_bit_cast(float, (uint32_t)u << 16);
}
// async global->LDS, 16B per lane; LDS dest = wave-uniform base + lane*16
__device__ __forceinline__ void gll16(void* lds, const void* g) {
  __builtin_amdgcn_global_load_lds(
      (const __attribute__((address_space(1))) void*)g,
      (__attribute__((address_space(3))) void*)lds, 16, 0, 0);
}

// ---------------------------------------------------------------------------
// One kernel converts x, w_attn, w_proj -> contiguous bf16 region.
// ---------------------------------------------------------------------------
__global__ __launch_bounds__(256) void cvt_all(const float* __restrict__ x,
                                               const float* __restrict__ wa,
                                               const float* __restrict__ wp,
                                               ushort* __restrict__ out) {
  static_assert(X4_ == 1048576 && WA4_ == 786432 && WP4_ == 262144, "sizes");
  static_assert((X4_ % 256) == 0 && ((X4_ + WA4_) % 256) == 0, "block-uniform");
  int i = blockIdx.x * 256 + threadIdx.x;      // 0 .. TOT4_-1
  const float* src; int off;
  if (i < X4_)              { src = x;  off = i; }
  else if (i < X4_ + WA4_)  { src = wa; off = i - X4_; }
  else                      { src = wp; off = i - (X4_ + WA4_); }
  float4 v = ((const float4*)src)[off];
  ushort4 o;
  o.x = f2bf(v.x); o.y = f2bf(v.y); o.z = f2bf(v.z); o.w = f2bf(v.w);
  ((ushort4*)out)[i] = o;
}

// ---------------------------------------------------------------------------
// QKV GEMM: qkv[m][f] = sum_k x[m][k]*w_attn[f][k], bf16 in/out.
// 128(M)x64(N) tile, BK=64, 256 thr (2x2 waves, each 64(M)x32(N) = 4x2 frags).
// Grid 32x48 = 1536 blocks -> 6 blocks/CU (24 KB LDS), 24 waves/CU — the
// resident-block lever that gave gemm_proj +33% (R15). Linear dispatch:
// consecutive bx share the same B-tile (128 KB) -> L2-friendly.
// Epilogue: q,k -> bf16 qkv (n0 < 2C); v -> vT[b][h][d][t] (64 | n0 -> one
// head per tile, block-uniform).
// ---------------------------------------------------------------------------
__global__ __launch_bounds__(256) void gemm_qkv(
    const ushort* __restrict__ A, const ushort* __restrict__ Bm,
    ushort* __restrict__ qkv, ushort* __restrict__ vT,
    int M, int N, int K)
{
  __shared__ ushort As[128][64];   // 16 KB
  __shared__ ushort Bs[64][64];    //  8 KB
  const int tid  = threadIdx.x;
  const int lane = tid & 63, w = tid >> 6;
  const int wr = w >> 1, wc = w & 1;
  const int ll = lane & 15, lg = lane >> 4;
  const int r8 = lane >> 3;
  const int gc = ((lane & 7) ^ r8) << 3;   // swizzled global chunk offset (elems)
  const int m0 = blockIdx.x * 128, n0 = blockIdx.y * 64;

  f32x4 acc[4][2] = {};

  for (int k0 = 0; k0 < K; k0 += 64) {
    __syncthreads();
    // A: 128 rows (4 issues of 32 rows), B: 64 rows (2 issues)
#pragma unroll
    for (int iss = 0; iss < 4; ++iss) {
      int rb = w * 32 + iss * 8;
      gll16(&As[rb][0], A + (size_t)(m0 + rb + r8) * K + k0 + gc);
    }
#pragma unroll
    for (int iss = 0; iss < 2; ++iss) {
      int rb = w * 16 + iss * 8;
      gll16(&Bs[rb][0], Bm + (size_t)(n0 + rb + r8) * K + k0 + gc);
    }
    __syncthreads();                        // drains vmcnt+lgkmcnt
#pragma unroll
    for (int ks = 0; ks < 2; ++ks) {
      const int sw = ((ks * 4 + lg) ^ (ll & 7)) * 8;
      bf16x8 af[4], bfr[2];
#pragma unroll
      for (int mi = 0; mi < 4; ++mi)
        af[mi] = *(const bf16x8*)&As[wr * 64 + mi * 16 + ll][sw];
#pragma unroll
      for (int ni = 0; ni < 2; ++ni)
        bfr[ni] = *(const bf16x8*)&Bs[wc * 32 + ni * 16 + ll][sw];
#pragma unroll
      for (int mi = 0; mi < 4; ++mi)
#pragma unroll
        for (int ni = 0; ni < 2; ++ni)
          acc[mi][ni] = __builtin_amdgcn_mfma_f32_16x16x32_bf16(
              af[mi], bfr[ni], acc[mi][ni], 0, 0, 0);
    }
  }

  // C/D layout: col = lane&15, row = (lane>>4)*4 + reg
  const int mrow = wr * 64 + lg * 4;
  const int ncol = wc * 32 + ll;
  if (n0 < 2 * C_) {                      // q,k region -> bf16 qkv
#pragma unroll
    for (int mi = 0; mi < 4; ++mi)
#pragma unroll
      for (int ni = 0; ni < 2; ++ni)
#pragma unroll
        for (int r = 0; r < 4; ++r)
          qkv[(size_t)(m0 + mrow + mi * 16 + r) * F3_ + n0 + ncol + ni * 16] =
              f2bf(acc[mi][ni][r]);
  } else {                                // v region -> vT[b][h][d][t]
    const int bb = m0 >> 11;
    const int tb = (m0 & 2047) + mrow;
    const int hh = (n0 - 2 * C_) >> 6;    // block-uniform (64 | n0)
#pragma unroll
    for (int mi = 0; mi < 4; ++mi)
#pragma unroll
      for (int ni = 0; ni < 2; ++ni) {
        int d = (n0 + ncol + ni * 16 - 2 * C_) & 63;
        ushort4 o;
        o.x = f2bf(acc[mi][ni][0]); o.y = f2bf(acc[mi][ni][1]);
        o.z = f2bf(acc[mi][ni][2]); o.w = f2bf(acc[mi][ni][3]);
        *(ushort4*)&vT[(((size_t)(bb * H_ + hh) * HD_ + d) << 11) + tb + mi * 16] = o;
      }
  }
}

// ---------------------------------------------------------------------------
// Output-projection GEMM (R15-proven): out[m][n] = sum_k y[m][k]*wp[n][k].
// 64x128 tile, 4 waves split on N, grid 64x8 = 512 blocks -> 2 blocks/CU.
// ---------------------------------------------------------------------------
__global__ __launch_bounds__(256) void gemm_proj(
    const ushort* __restrict__ A, const ushort* __restrict__ Bm,
    float* __restrict__ C, int M, int N, int K)
{
  __shared__ ushort As[64][64];    // 8 KB
  __shared__ ushort Bs[128][64];   // 16 KB
  const int tid  = threadIdx.x;
  const int lane = tid & 63, w = tid >> 6;
  const int ll = lane & 15, lg = lane >> 4;
  const int r8 = lane >> 3;
  const int gc = ((lane & 7) ^ r8) << 3;
  const int m0 = blockIdx.x * 64, n0 = blockIdx.y * 128;

  f32x4 acc[4][2] = {};

  for (int k0 = 0; k0 < K; k0 += 64) {
    __syncthreads();
#pragma unroll
    for (int iss = 0; iss < 2; ++iss) {
      int rb = w * 16 + iss * 8;
      gll16(&As[rb][0], A + (size_t)(m0 + rb + r8) * K + k0 + gc);
    }
#pragma unroll
    for (int iss = 0; iss < 4; ++iss) {
      int rb = w * 32 + iss * 8;
      gll16(&Bs[rb][0], Bm + (size_t)(n0 + rb + r8) * K + k0 + gc);
    }
    __syncthreads();                        // drains vmcnt+lgkmcnt
#pragma unroll
    for (int ks = 0; ks < 2; ++ks) {
      const int sw = ((ks * 4 + lg) ^ (ll & 7)) * 8;
      bf16x8 af[4], bfr[2];
#pragma unroll
      for (int mi = 0; mi < 4; ++mi)
        af[mi] = *(const bf16x8*)&As[mi * 16 + ll][sw];        // broadcast rows
#pragma unroll
      for (int ni = 0; ni < 2; ++ni)
        bfr[ni] = *(const bf16x8*)&Bs[w * 32 + ni * 16 + ll][sw];
#pragma unroll
      for (int mi = 0; mi < 4; ++mi)
#pragma unroll
        for (int ni = 0; ni < 2; ++ni)
          acc[mi][ni] = __builtin_amdgcn_mfma_f32_16x16x32_bf16(
              af[mi], bfr[ni], acc[mi][ni], 0, 0, 0);
    }
  }

  // C/D layout: col = lane&15, row = (lane>>4)*4 + reg
#pragma unroll
  for (int mi = 0; mi < 4; ++mi)
#pragma unroll
    for (int ni = 0; ni < 2; ++ni)
#pragma unroll
      for (int r = 0; r < 4; ++r)
        C[(size_t)(m0 + mi * 16 + lg * 4 + r) * N + n0 + w * 32 + ni * 16 + ll] =
            acc[mi][ni][r];
}

// ---------------------------------------------------------------------------
// RoPE in-place on bf16 q,k. Folds 1/sqrt(HD)*log2(e) into q so attention
// softmax can use native exp2 (v_exp_f32) with no pre-multiply.
// ---------------------------------------------------------------------------
#define QSC 0.18033688f   // 0.125 * log2(e)
__global__ __launch_bounds__(256) void rope_bf(ushort* __restrict__ qkv,
                                               const float* __restrict__ fcos,
                                               const float* __restrict__ fsin) {
  int idx = blockIdx.x * 256 + threadIdx.x;   // B*T*H*16
  int i2 = idx & 15;
  int h  = (idx >> 4) & 15;
  int t  = (idx >> 8) & 2047;
  int b  = idx >> 19;
  int fi = t * 32 + i2 * 2;
  float c0 = fcos[fi], s0 = fsin[fi], c1 = fcos[fi + 1], s1 = fsin[fi + 1];
  size_t base = (size_t)(b * T_ + t) * F3_ + h * HD_ + i2 * 4;
  ushort4 qv = *(ushort4*)&qkv[base];
  ushort4 qo;
  { float e = bf2f(qv.x), o = bf2f(qv.y);
    qo.x = f2bf((e * c0 - o * s0) * QSC);
    qo.y = f2bf((e * s0 + o * c0) * QSC); }
  { float e = bf2f(qv.z), o = bf2f(qv.w);
    qo.z = f2bf((e * c1 - o * s1) * QSC);
    qo.w = f2bf((e * s1 + o * c1) * QSC); }
  *(ushort4*)&qkv[base] = qo;
  ushort4 kv = *(ushort4*)&qkv[base + C_];
  ushort4 ko;
  { float e = bf2f(kv.x), o = bf2f(kv.y);
    ko.x = f2bf(e * c0 - o * s0);
    ko.y = f2bf(e * s0 + o * c0); }
  { float e = bf2f(kv.z), o = bf2f(kv.w);
    ko.z = f2bf(e * c1 - o * s1);
    ko.w = f2bf(e * s1 + o * c1); }
  *(ushort4*)&qkv[base + C_] = ko;
}

// ---------------------------------------------------------------------------
// Flash attention (R7 version, verbatim — measured 45.5 us best): bf16 MFMA,
// swapped-QK^T in-lane softmax (exp2 domain), dbuf K/V. 4 waves/block, 64
// Q-rows, KV tiles 64. sacc[j][r] = S^T[key = j*16+lg*4+r][qrow = ll].
// ---------------------------------------------------------------------------
__global__ __launch_bounds__(256) void attn_mfma(
    const ushort* __restrict__ qkv, const ushort* __restrict__ vT,
    ushort* __restrict__ y)
{
  __shared__ __align__(16) ushort Qs[64][64];
  __shared__ __align__(16) ushort Ks[2][64][64], VTs[2][64][64];
  __shared__ __align__(16) ushort Ps[4][16][72];

  const int qt = 31 - blockIdx.y;        // heavy tiles first
  const int bh = blockIdx.x;
  const int b = bh >> 4, h = bh & 15;
  const int q0 = qt * 64;
  const int tid = threadIdx.x, lane = tid & 63, w = tid >> 6;
  const int ll = lane & 15, lg = lane >> 4;
  const int r8 = lane >> 3;
  const int gc = ((lane & 7) ^ r8) << 3;
  const float NEG = -3.0e38f;

  const ushort* qb = qkv + (size_t)(b * T_) * F3_ + h * HD_;
  const ushort* kb = qb + C_;
  const ushort* vb = vT + ((size_t)(b * H_ + h) * HD_ << 11);

  // prologue: stage Q and K/V tile 0 into buf 0
#pragma unroll
  for (int iss = 0; iss < 2; ++iss) {
    int rb = w * 16 + iss * 8;
    gll16(&Qs[rb][0], qb + (size_t)(q0 + rb + r8) * F3_ + gc);
    gll16(&Ks[0][rb][0],  kb + (size_t)(rb + r8) * F3_ + gc);
    gll16(&VTs[0][rb][0], vb + ((size_t)(rb + r8) << 11) + gc);
  }
  __syncthreads();

  bf16x8 qf[2];
#pragma unroll
  for (int ks = 0; ks < 2; ++ks)
    qf[ks] = *(const bf16x8*)&Qs[w * 16 + ll][((ks * 4 + lg) ^ (ll & 7)) * 8];

  f32x4 oacc[4] = {};
  float m_ = NEG, l_ = 0.f;
  int cur = 0;

  for (int kt = 0; kt <= qt; ++kt) {
    // issue next tile's async loads (overlap with this tile's compute)
    if (kt < qt) {
#pragma unroll
      for (int iss = 0; iss < 2; ++iss) {
        int rb = w * 16 + iss * 8;
        gll16(&Ks[cur ^ 1][rb][0],
              kb + (size_t)((kt + 1) * 64 + rb + r8) * F3_ + gc);
        gll16(&VTs[cur ^ 1][rb][0],
              vb + ((size_t)(rb + r8) << 11) + (kt + 1) * 64 + gc);
      }
    }

    // ---- S^T = K Q^T ----
    f32x4 sacc[4] = {};
#pragma unroll
    for (int ks = 0; ks < 2; ++ks) {
      const int sw = ((ks * 4 + lg) ^ (ll & 7)) * 8;
      bf16x8 kf[4];
#pragma unroll
      for (int j = 0; j < 4; ++j)
        kf[j] = *(const bf16x8*)&Ks[cur][j * 16 + ll][sw];
      __builtin_amdgcn_s_setprio(1);
#pragma unroll
      for (int j = 0; j < 4; ++j)
        sacc[j] = __builtin_amdgcn_mfma_f32_16x16x32_bf16(kf[j], qf[ks], sacc[j], 0, 0, 0);
      __builtin_amdgcn_s_setprio(0);
    }

    if (kt == qt) {                       // causal mask on diagonal tile
#pragma unroll
      for (int j = 0; j < 4; ++j)
#pragma unroll
        for (int r = 0; r < 4; ++r)
          if (j * 16 + lg * 4 + r > w * 16 + ll) sacc[j][r] = NEG;
    }

    // ---- in-lane online softmax, exp2 domain (row = ll) ----
    float tmax;
    {
      float t0 = fmaxf(fmaxf(sacc[0][0], sacc[0][1]), fmaxf(sacc[0][2], sacc[0][3]));
      float t1 = fmaxf(fmaxf(sacc[1][0], sacc[1][1]), fmaxf(sacc[1][2], sacc[1][3]));
      float t2 = fmaxf(fmaxf(sacc[2][0], sacc[2][1]), fmaxf(sacc[2][2], sacc[2][3]));
      float t3 = fmaxf(fmaxf(sacc[3][0], sacc[3][1]), fmaxf(sacc[3][2], sacc[3][3]));
      tmax = fmaxf(fmaxf(t0, t1), fmaxf(t2, t3));
      tmax = fmaxf(tmax, __shfl_xor(tmax, 16));
      tmax = fmaxf(tmax, __shfl_xor(tmax, 32));
    }
    if (!__all(tmax <= m_ + 11.5441f)) {  // defer-max (8 nats in log2 units)
      float mnew = fmaxf(m_, tmax);
      float al = __builtin_amdgcn_exp2f(m_ - mnew);   // 0 on first tile
      l_ *= al;
      m_ = mnew;
#pragma unroll
      for (int r = 0; r < 4; ++r) {
        float alr = __shfl(al, lg * 4 + r);
#pragma unroll
        for (int dj = 0; dj < 4; ++dj) oacc[dj][r] *= alr;
      }
    }
    float psum = 0.f;
#pragma unroll
    for (int j = 0; j < 4; ++j) {
      float p0 = __builtin_amdgcn_exp2f(sacc[j][0] - m_);
      float p1 = __builtin_amdgcn_exp2f(sacc[j][1] - m_);
      float p2 = __builtin_amdgcn_exp2f(sacc[j][2] - m_);
      float p3 = __builtin_amdgcn_exp2f(sacc[j][3] - m_);
      psum += (p0 + p1) + (p2 + p3);
      // truncating bf16 pack (probabilities: RNE not needed)
      uint u0 = __builtin_bit_cast(uint32_t, p0) >> 16;
      uint u1 = __builtin_bit_cast(uint32_t, p1) & 0xffff0000u;
      uint u2 = __builtin_bit_cast(uint32_t, p2) >> 16;
      uint u3 = __builtin_bit_cast(uint32_t, p3) & 0xffff0000u;
      uint2 pk = make_uint2(u0 | u1, u2 | u3);
      *(uint2*)&Ps[w][ll][j * 16 + lg * 4] = pk;
    }
    psum += __shfl_xor(psum, 16);
    psum += __shfl_xor(psum, 32);
    l_ += psum;

    // ---- O += P V ----
#pragma unroll
    for (int ks = 0; ks < 2; ++ks) {
      bf16x8 pf = *(const bf16x8*)&Ps[w][ll][ks * 32 + lg * 8];
      const int sw = ((ks * 4 + lg) ^ (ll & 7)) * 8;
      bf16x8 vf[4];
#pragma unroll
      for (int dj = 0; dj < 4; ++dj)
        vf[dj] = *(const bf16x8*)&VTs[cur][dj * 16 + ll][sw];
      __builtin_amdgcn_s_setprio(1);
#pragma unroll
      for (int dj = 0; dj < 4; ++dj)
        oacc[dj] = __builtin_amdgcn_mfma_f32_16x16x32_bf16(pf, vf[dj], oacc[dj], 0, 0, 0);
      __builtin_amdgcn_s_setprio(0);
    }

    __syncthreads();   // all waves done with buf[cur]; next buf staged
    cur ^= 1;
  }

  // epilogue: broadcast l for rows lg*4+r, normalize, store bf16
#pragma unroll
  for (int r = 0; r < 4; ++r) {
    float lr = __shfl(l_, lg * 4 + r);
    float inv = 1.0f / lr;
    int row = q0 + w * 16 + lg * 4 + r;
#pragma unroll
    for (int dj = 0; dj < 4; ++dj)
      y[(size_t)(b * T_ + row) * C_ + h * HD_ + dj * 16 + ll] =
          f2bf(oacc[dj][r] * inv);
  }
}

// ---------------------------------------------------------------------------
extern "C" void kernel_launch(void* const* d_in, const int* in_sizes, int n_in,
                              void* d_out, int out_size, void* d_ws, size_t ws_size,
                              hipStream_t stream) {
  const float* x      = (const float*)d_in[0];
  const float* w_attn = (const float*)d_in[1];
  const float* w_proj = (const float*)d_in[2];
  const float* fcos   = (const float*)d_in[3];
  const float* fsin   = (const float*)d_in[4];
  float* out = (float*)d_out;

  ushort* xb   = (ushort*)d_ws;                 // 4096x1024 bf16
  ushort* wab  = xb   + (size_t)4096 * 1024;    // 3072x1024
  ushort* wpb  = wab  + (size_t)3072 * 1024;    // 1024x1024
  ushort* qkvb = wpb  + (size_t)1024 * 1024;    // 4096x3072 (q,k only)
  ushort* vt   = qkvb + (size_t)4096 * 3072;    // [2][16][64][2048]
  ushort* yb   = vt   + (size_t)32 * 64 * 2048; // 4096x1024

  cvt_all<<<TOT4_ / 256, 256, 0, stream>>>(x, w_attn, w_proj, xb);

  { dim3 g(32, 48); gemm_qkv<<<g, 256, 0, stream>>>(xb, wab, qkvb, vt, 4096, F3_, C_); }
  rope_bf<<<4096, 256, 0, stream>>>(qkvb, fcos, fsin);
  { dim3 g(32, 32); attn_mfma<<<g, 256, 0, stream>>>(qkvb, vt, yb); }
  { dim3 g(64, 8);  gemm_proj<<<g, 256, 0, stream>>>(yb, wpb, out, 4096, C_, C_); }
}

// Round 17
// 108.014 us; speedup vs baseline: 1.0584x; 1.0584x over previous
//
#include <hip/hip_runtime.h>
#include <math.h>

#define B_  2
#define T_  2048
#define C_  1024
#define H_  16
#define HD_ 64
#define F3_ 3072   // 3*C

// float4 unit counts for cvt_all (derived, not hand-copied):
#define X4_   ((B_ * T_ * C_) / 4)         // 2*2048*1024/4 = 1,048,576
#define WA4_  ((F3_ * C_) / 4)             // 3072*1024/4   =   786,432
#define WP4_  ((C_ * C_) / 4)              // 1024*1024/4   =   262,144
#define TOT4_ (X4_ + WA4_ + WP4_)          //               = 2,097,152 = 8192*256

typedef __attribute__((ext_vector_type(8))) __bf16 bf16x8;
typedef __attribute__((ext_vector_type(4))) float  f32x4;

__device__ __forceinline__ ushort f2bf(float f) {
  uint32_t u = __builtin_bit_cast(uint32_t, f);
  u += 0x7fff + ((u >> 16) & 1);        // RNE
  return (ushort)(u >> 16);
}
__device__ __forceinline__ float bf2f(ushort u) {
  return __builtin_bit_cast(float, (uint32_t)u << 16);
}
// async global->LDS, 16B per lane; LDS dest = wave-uniform base + lane*16
__device__ __forceinline__ void gll16(void* lds, const void* g) {
  __builtin_amdgcn_global_load_lds(
      (const __attribute__((address_space(1))) void*)g,
      (__attribute__((address_space(3))) void*)lds, 16, 0, 0);
}

// ---------------------------------------------------------------------------
// One kernel converts x, w_attn, w_proj -> contiguous bf16 region.
// ---------------------------------------------------------------------------
__global__ __launch_bounds__(256) void cvt_all(const float* __restrict__ x,
                                               const float* __restrict__ wa,
                                               const float* __restrict__ wp,
                                               ushort* __restrict__ out) {
  static_assert(X4_ == 1048576 && WA4_ == 786432 && WP4_ == 262144, "sizes");
  static_assert((X4_ % 256) == 0 && ((X4_ + WA4_) % 256) == 0, "block-uniform");
  int i = blockIdx.x * 256 + threadIdx.x;      // 0 .. TOT4_-1
  const float* src; int off;
  if (i < X4_)              { src = x;  off = i; }
  else if (i < X4_ + WA4_)  { src = wa; off = i - X4_; }
  else                      { src = wp; off = i - (X4_ + WA4_); }
  float4 v = ((const float4*)src)[off];
  ushort4 o;
  o.x = f2bf(v.x); o.y = f2bf(v.y); o.z = f2bf(v.z); o.w = f2bf(v.w);
  ((ushort4*)out)[i] = o;
}

// ---------------------------------------------------------------------------
// bf16 MFMA GEMM (qkv), B^T weights: C[m][n] = sum_k A[m][k]*Bm[n][k].
// 128x128 tile, BK=64, 256 thr (2x2 waves, each 64x64 = 4x4 frags of 16x16).
// XCD 2D-patch swizzle. MODE 1 epilogue: q,k -> bf16 qkv; v -> vT[b][h][d][t].
// ---------------------------------------------------------------------------
template<int MODE>
__global__ __launch_bounds__(256) void gemm_mfma(
    const ushort* __restrict__ A, const ushort* __restrict__ Bm,
    void* __restrict__ Cout, ushort* __restrict__ vT,
    int M, int N, int K)
{
  __shared__ ushort As[128][64];
  __shared__ ushort Bs[128][64];
  const int tid  = threadIdx.x;
  const int lane = tid & 63, w = tid >> 6;
  const int wr = w >> 1, wc = w & 1;
  const int ll = lane & 15, lg = lane >> 4;
  const int r8 = lane >> 3;
  const int gc = ((lane & 7) ^ r8) << 3;   // swizzled global chunk offset (elems)
  const int lid = blockIdx.y * gridDim.x + blockIdx.x;
  const int j = lid & 7, g = lid >> 3;
  const int m0 = ((j & 3) * 8 + (g & 7)) * 128;
  const int n0 = ((j >> 2) * (N >> 8) + (g >> 3)) * 128;

  f32x4 acc[4][4] = {};

  for (int k0 = 0; k0 < K; k0 += 64) {
    __syncthreads();
#pragma unroll
    for (int iss = 0; iss < 4; ++iss) {
      int rb = w * 32 + iss * 8;           // wave-uniform LDS row base
      gll16(&As[rb][0], A  + (size_t)(m0 + rb + r8) * K + k0 + gc);
      gll16(&Bs[rb][0], Bm + (size_t)(n0 + rb + r8) * K + k0 + gc);
    }
    __syncthreads();                        // drains vmcnt+lgkmcnt
#pragma unroll
    for (int ks = 0; ks < 2; ++ks) {
      const int sw = ((ks * 4 + lg) ^ (ll & 7)) * 8;
      bf16x8 af[4], bfr[4];
#pragma unroll
      for (int mi = 0; mi < 4; ++mi)
        af[mi] = *(const bf16x8*)&As[wr * 64 + mi * 16 + ll][sw];
#pragma unroll
      for (int ni = 0; ni < 4; ++ni)
        bfr[ni] = *(const bf16x8*)&Bs[wc * 64 + ni * 16 + ll][sw];
#pragma unroll
      for (int mi = 0; mi < 4; ++mi)
#pragma unroll
        for (int ni = 0; ni < 4; ++ni)
          acc[mi][ni] = __builtin_amdgcn_mfma_f32_16x16x32_bf16(
              af[mi], bfr[ni], acc[mi][ni], 0, 0, 0);
    }
  }

  // C/D layout: col = lane&15, row = (lane>>4)*4 + reg
  const int mrow = wr * 64 + lg * 4;
  const int ncol = wc * 64 + ll;
  if (MODE == 0) {
    float* C = (float*)Cout;
#pragma unroll
    for (int mi = 0; mi < 4; ++mi)
#pragma unroll
      for (int ni = 0; ni < 4; ++ni)
#pragma unroll
        for (int r = 0; r < 4; ++r)
          C[(size_t)(m0 + mrow + mi * 16 + r) * N + n0 + ncol + ni * 16] =
              acc[mi][ni][r];
  } else {
    if (n0 < 2 * C_) {                      // q,k region -> bf16 qkv
      ushort* q = (ushort*)Cout;
#pragma unroll
      for (int mi = 0; mi < 4; ++mi)
#pragma unroll
        for (int ni = 0; ni < 4; ++ni)
#pragma unroll
          for (int r = 0; r < 4; ++r)
            q[(size_t)(m0 + mrow + mi * 16 + r) * F3_ + n0 + ncol + ni * 16] =
                f2bf(acc[mi][ni][r]);
    } else {                                // v region -> vT[b][h][d][t]
      const int bb = m0 >> 11;
      const int tb = (m0 & 2047) + mrow;
#pragma unroll
      for (int mi = 0; mi < 4; ++mi)
#pragma unroll
        for (int ni = 0; ni < 4; ++ni) {
          int f  = n0 + ncol + ni * 16 - 2 * C_;
          int hh = f >> 6, d = f & 63;
          ushort4 o;
          o.x = f2bf(acc[mi][ni][0]); o.y = f2bf(acc[mi][ni][1]);
          o.z = f2bf(acc[mi][ni][2]); o.w = f2bf(acc[mi][ni][3]);
          *(ushort4*)&vT[(((size_t)(bb * H_ + hh) * HD_ + d) << 11) + tb + mi * 16] = o;
        }
    }
  }
}

// ---------------------------------------------------------------------------
// Output-projection GEMM: out[m][n] = sum_k y[m][k]*w_proj[n][k], fp32 out.
// 64x128 tile, BK=64, 256 thr = 4 waves SPLIT ON N (wave w -> cols w*32..+31,
// frags 4(M) x 2(N)). Grid 64x8 = 512 blocks -> 2 blocks/CU = 8 waves/CU.
// LDS 24 KB. w_proj (2 MB) is fully L2-resident.
// ---------------------------------------------------------------------------
__global__ __launch_bounds__(256) void gemm_proj(
    const ushort* __restrict__ A, const ushort* __restrict__ Bm,
    float* __restrict__ C, int M, int N, int K)
{
  __shared__ ushort As[64][64];    // 8 KB
  __shared__ ushort Bs[128][64];   // 16 KB
  const int tid  = threadIdx.x;
  const int lane = tid & 63, w = tid >> 6;
  const int ll = lane & 15, lg = lane >> 4;
  const int r8 = lane >> 3;
  const int gc = ((lane & 7) ^ r8) << 3;
  const int m0 = blockIdx.x * 64, n0 = blockIdx.y * 128;

  f32x4 acc[4][2] = {};

  for (int k0 = 0; k0 < K; k0 += 64) {
    __syncthreads();
    // A: 64 rows, 2 issues of 32 rows (4 waves x 8 rows)
#pragma unroll
    for (int iss = 0; iss < 2; ++iss) {
      int rb = w * 16 + iss * 8;
      gll16(&As[rb][0], A + (size_t)(m0 + rb + r8) * K + k0 + gc);
    }
    // B: 128 rows, 4 issues of 32 rows
#pragma unroll
    for (int iss = 0; iss < 4; ++iss) {
      int rb = w * 32 + iss * 8;
      gll16(&Bs[rb][0], Bm + (size_t)(n0 + rb + r8) * K + k0 + gc);
    }
    __syncthreads();                        // drains vmcnt+lgkmcnt
#pragma unroll
    for (int ks = 0; ks < 2; ++ks) {
      const int sw = ((ks * 4 + lg) ^ (ll & 7)) * 8;
      bf16x8 af[4], bfr[2];
#pragma unroll
      for (int mi = 0; mi < 4; ++mi)
        af[mi] = *(const bf16x8*)&As[mi * 16 + ll][sw];        // broadcast rows
#pragma unroll
      for (int ni = 0; ni < 2; ++ni)
        bfr[ni] = *(const bf16x8*)&Bs[w * 32 + ni * 16 + ll][sw];
#pragma unroll
      for (int mi = 0; mi < 4; ++mi)
#pragma unroll
        for (int ni = 0; ni < 2; ++ni)
          acc[mi][ni] = __builtin_amdgcn_mfma_f32_16x16x32_bf16(
              af[mi], bfr[ni], acc[mi][ni], 0, 0, 0);
    }
  }

  // C/D layout: col = lane&15, row = (lane>>4)*4 + reg
#pragma unroll
  for (int mi = 0; mi < 4; ++mi)
#pragma unroll
    for (int ni = 0; ni < 2; ++ni)
#pragma unroll
      for (int r = 0; r < 4; ++r)
        C[(size_t)(m0 + mi * 16 + lg * 4 + r) * N + n0 + w * 32 + ni * 16 + ll] =
            acc[mi][ni][r];
}

// ---------------------------------------------------------------------------
// RoPE in-place on bf16 q,k. Folds 1/sqrt(HD)*log2(e) into q so attention
// softmax can use native exp2 (v_exp_f32) with no pre-multiply.
// ---------------------------------------------------------------------------
#define QSC 0.18033688f   // 0.125 * log2(e)
__global__ __launch_bounds__(256) void rope_bf(ushort* __restrict__ qkv,
                                               const float* __restrict__ fcos,
                                               const float* __restrict__ fsin) {
  int idx = blockIdx.x * 256 + threadIdx.x;   // B*T*H*16
  int i2 = idx & 15;
  int h  = (idx >> 4) & 15;
  int t  = (idx >> 8) & 2047;
  int b  = idx >> 19;
  int fi = t * 32 + i2 * 2;
  float c0 = fcos[fi], s0 = fsin[fi], c1 = fcos[fi + 1], s1 = fsin[fi + 1];
  size_t base = (size_t)(b * T_ + t) * F3_ + h * HD_ + i2 * 4;
  ushort4 qv = *(ushort4*)&qkv[base];
  ushort4 qo;
  { float e = bf2f(qv.x), o = bf2f(qv.y);
    qo.x = f2bf((e * c0 - o * s0) * QSC);
    qo.y = f2bf((e * s0 + o * c0) * QSC); }
  { float e = bf2f(qv.z), o = bf2f(qv.w);
    qo.z = f2bf((e * c1 - o * s1) * QSC);
    qo.w = f2bf((e * s1 + o * c1) * QSC); }
  *(ushort4*)&qkv[base] = qo;
  ushort4 kv = *(ushort4*)&qkv[base + C_];
  ushort4 ko;
  { float e = bf2f(kv.x), o = bf2f(kv.y);
    ko.x = f2bf(e * c0 - o * s0);
    ko.y = f2bf(e * s0 + o * c0); }
  { float e = bf2f(kv.z), o = bf2f(kv.w);
    ko.z = f2bf(e * c1 - o * s1);
    ko.w = f2bf(e * s1 + o * c1); }
  *(ushort4*)&qkv[base + C_] = ko;
}

// ---------------------------------------------------------------------------
// Flash attention (R7 version, verbatim — measured 45.5 us best): bf16 MFMA,
// swapped-QK^T in-lane softmax (exp2 domain), dbuf K/V. 4 waves/block, 64
// Q-rows, KV tiles 64. sacc[j][r] = S^T[key = j*16+lg*4+r][qrow = ll].
// ---------------------------------------------------------------------------
__global__ __launch_bounds__(256) void attn_mfma(
    const ushort* __restrict__ qkv, const ushort* __restrict__ vT,
    ushort* __restrict__ y)
{
  __shared__ __align__(16) ushort Qs[64][64];
  __shared__ __align__(16) ushort Ks[2][64][64], VTs[2][64][64];
  __shared__ __align__(16) ushort Ps[4][16][72];

  const int qt = 31 - blockIdx.y;        // heavy tiles first
  const int bh = blockIdx.x;
  const int b = bh >> 4, h = bh & 15;
  const int q0 = qt * 64;
  const int tid = threadIdx.x, lane = tid & 63, w = tid >> 6;
  const int ll = lane & 15, lg = lane >> 4;
  const int r8 = lane >> 3;
  const int gc = ((lane & 7) ^ r8) << 3;
  const float NEG = -3.0e38f;

  const ushort* qb = qkv + (size_t)(b * T_) * F3_ + h * HD_;
  const ushort* kb = qb + C_;
  const ushort* vb = vT + ((size_t)(b * H_ + h) * HD_ << 11);

  // prologue: stage Q and K/V tile 0 into buf 0
#pragma unroll
  for (int iss = 0; iss < 2; ++iss) {
    int rb = w * 16 + iss * 8;
    gll16(&Qs[rb][0], qb + (size_t)(q0 + rb + r8) * F3_ + gc);
    gll16(&Ks[0][rb][0],  kb + (size_t)(rb + r8) * F3_ + gc);
    gll16(&VTs[0][rb][0], vb + ((size_t)(rb + r8) << 11) + gc);
  }
  __syncthreads();

  bf16x8 qf[2];
#pragma unroll
  for (int ks = 0; ks < 2; ++ks)
    qf[ks] = *(const bf16x8*)&Qs[w * 16 + ll][((ks * 4 + lg) ^ (ll & 7)) * 8];

  f32x4 oacc[4] = {};
  float m_ = NEG, l_ = 0.f;
  int cur = 0;

  for (int kt = 0; kt <= qt; ++kt) {
    // issue next tile's async loads (overlap with this tile's compute)
    if (kt < qt) {
#pragma unroll
      for (int iss = 0; iss < 2; ++iss) {
        int rb = w * 16 + iss * 8;
        gll16(&Ks[cur ^ 1][rb][0],
              kb + (size_t)((kt + 1) * 64 + rb + r8) * F3_ + gc);
        gll16(&VTs[cur ^ 1][rb][0],
              vb + ((size_t)(rb + r8) << 11) + (kt + 1) * 64 + gc);
      }
    }

    // ---- S^T = K Q^T ----
    f32x4 sacc[4] = {};
#pragma unroll
    for (int ks = 0; ks < 2; ++ks) {
      const int sw = ((ks * 4 + lg) ^ (ll & 7)) * 8;
      bf16x8 kf[4];
#pragma unroll
      for (int j = 0; j < 4; ++j)
        kf[j] = *(const bf16x8*)&Ks[cur][j * 16 + ll][sw];
      __builtin_amdgcn_s_setprio(1);
#pragma unroll
      for (int j = 0; j < 4; ++j)
        sacc[j] = __builtin_amdgcn_mfma_f32_16x16x32_bf16(kf[j], qf[ks], sacc[j], 0, 0, 0);
      __builtin_amdgcn_s_setprio(0);
    }

    if (kt == qt) {                       // causal mask on diagonal tile
#pragma unroll
      for (int j = 0; j < 4; ++j)
#pragma unroll
        for (int r = 0; r < 4; ++r)
          if (j * 16 + lg * 4 + r > w * 16 + ll) sacc[j][r] = NEG;
    }

    // ---- in-lane online softmax, exp2 domain (row = ll) ----
    float tmax;
    {
      float t0 = fmaxf(fmaxf(sacc[0][0], sacc[0][1]), fmaxf(sacc[0][2], sacc[0][3]));
      float t1 = fmaxf(fmaxf(sacc[1][0], sacc[1][1]), fmaxf(sacc[1][2], sacc[1][3]));
      float t2 = fmaxf(fmaxf(sacc[2][0], sacc[2][1]), fmaxf(sacc[2][2], sacc[2][3]));
      float t3 = fmaxf(fmaxf(sacc[3][0], sacc[3][1]), fmaxf(sacc[3][2], sacc[3][3]));
      tmax = fmaxf(fmaxf(t0, t1), fmaxf(t2, t3));
      tmax = fmaxf(tmax, __shfl_xor(tmax, 16));
      tmax = fmaxf(tmax, __shfl_xor(tmax, 32));
    }
    if (!__all(tmax <= m_ + 11.5441f)) {  // defer-max (8 nats in log2 units)
      float mnew = fmaxf(m_, tmax);
      float al = __builtin_amdgcn_exp2f(m_ - mnew);   // 0 on first tile
      l_ *= al;
      m_ = mnew;
#pragma unroll
      for (int r = 0; r < 4; ++r) {
        float alr = __shfl(al, lg * 4 + r);
#pragma unroll
        for (int dj = 0; dj < 4; ++dj) oacc[dj][r] *= alr;
      }
    }
    float psum = 0.f;
#pragma unroll
    for (int j = 0; j < 4; ++j) {
      float p0 = __builtin_amdgcn_exp2f(sacc[j][0] - m_);
      float p1 = __builtin_amdgcn_exp2f(sacc[j][1] - m_);
      float p2 = __builtin_amdgcn_exp2f(sacc[j][2] - m_);
      float p3 = __builtin_amdgcn_exp2f(sacc[j][3] - m_);
      psum += (p0 + p1) + (p2 + p3);
      // truncating bf16 pack (probabilities: RNE not needed)
      uint u0 = __builtin_bit_cast(uint32_t, p0) >> 16;
      uint u1 = __builtin_bit_cast(uint32_t, p1) & 0xffff0000u;
      uint u2 = __builtin_bit_cast(uint32_t, p2) >> 16;
      uint u3 = __builtin_bit_cast(uint32_t, p3) & 0xffff0000u;
      uint2 pk = make_uint2(u0 | u1, u2 | u3);
      *(uint2*)&Ps[w][ll][j * 16 + lg * 4] = pk;
    }
    psum += __shfl_xor(psum, 16);
    psum += __shfl_xor(psum, 32);
    l_ += psum;

    // ---- O += P V ----
#pragma unroll
    for (int ks = 0; ks < 2; ++ks) {
      bf16x8 pf = *(const bf16x8*)&Ps[w][ll][ks * 32 + lg * 8];
      const int sw = ((ks * 4 + lg) ^ (ll & 7)) * 8;
      bf16x8 vf[4];
#pragma unroll
      for (int dj = 0; dj < 4; ++dj)
        vf[dj] = *(const bf16x8*)&VTs[cur][dj * 16 + ll][sw];
      __builtin_amdgcn_s_setprio(1);
#pragma unroll
      for (int dj = 0; dj < 4; ++dj)
        oacc[dj] = __builtin_amdgcn_mfma_f32_16x16x32_bf16(pf, vf[dj], oacc[dj], 0, 0, 0);
      __builtin_amdgcn_s_setprio(0);
    }

    __syncthreads();   // all waves done with buf[cur]; next buf staged
    cur ^= 1;
  }

  // epilogue: broadcast l for rows lg*4+r, normalize, store bf16
#pragma unroll
  for (int r = 0; r < 4; ++r) {
    float lr = __shfl(l_, lg * 4 + r);
    float inv = 1.0f / lr;
    int row = q0 + w * 16 + lg * 4 + r;
#pragma unroll
    for (int dj = 0; dj < 4; ++dj)
      y[(size_t)(b * T_ + row) * C_ + h * HD_ + dj * 16 + ll] =
          f2bf(oacc[dj][r] * inv);
  }
}

// ---------------------------------------------------------------------------
extern "C" void kernel_launch(void* const* d_in, const int* in_sizes, int n_in,
                              void* d_out, int out_size, void* d_ws, size_t ws_size,
                              hipStream_t stream) {
  const float* x      = (const float*)d_in[0];
  const float* w_attn = (const float*)d_in[1];
  const float* w_proj = (const float*)d_in[2];
  const float* fcos   = (const float*)d_in[3];
  const float* fsin   = (const float*)d_in[4];
  float* out = (float*)d_out;

  ushort* xb   = (ushort*)d_ws;                 // 4096x1024 bf16
  ushort* wab  = xb   + (size_t)4096 * 1024;    // 3072x1024
  ushort* wpb  = wab  + (size_t)3072 * 1024;    // 1024x1024
  ushort* qkvb = wpb  + (size_t)1024 * 1024;    // 4096x3072 (q,k only)
  ushort* vt   = qkvb + (size_t)4096 * 3072;    // [2][16][64][2048]
  ushort* yb   = vt   + (size_t)32 * 64 * 2048; // 4096x1024

  cvt_all<<<TOT4_ / 256, 256, 0, stream>>>(x, w_attn, w_proj, xb);

  { dim3 g(32, 24); gemm_mfma<1><<<g, 256, 0, stream>>>(xb, wab, qkvb, vt, 4096, F3_, C_); }
  rope_bf<<<4096, 256, 0, stream>>>(qkvb, fcos, fsin);
  { dim3 g(32, 32); attn_mfma<<<g, 256, 0, stream>>>(qkvb, vt, yb); }
  { dim3 g(64, 8);  gemm_proj<<<g, 256, 0, stream>>>(yb, wpb, out, 4096, C_, C_); }
}

// Round 18
// 106.561 us; speedup vs baseline: 1.0728x; 1.0136x over previous
//
#include <hip/hip_runtime.h>
#include <math.h>

#define B_  2
#define T_  2048
#define C_  1024
#define H_  16
#define HD_ 64
#define F3_ 3072   // 3*C

// float4 unit counts for cvt_all (derived, not hand-copied):
#define X4_   ((B_ * T_ * C_) / 4)         // 2*2048*1024/4 = 1,048,576
#define WA4_  ((F3_ * C_) / 4)             // 3072*1024/4   =   786,432
#define WP4_  ((C_ * C_) / 4)              // 1024*1024/4   =   262,144
#define TOT4_ (X4_ + WA4_ + WP4_)          //               = 2,097,152 = 8192*256

typedef __attribute__((ext_vector_type(8))) __bf16 bf16x8;
typedef __attribute__((ext_vector_type(4))) float  f32x4;

__device__ __forceinline__ ushort f2bf(float f) {
  uint32_t u = __builtin_bit_cast(uint32_t, f);
  u += 0x7fff + ((u >> 16) & 1);        // RNE
  return (ushort)(u >> 16);
}
__device__ __forceinline__ float bf2f(ushort u) {
  return __builtin_bit_cast(float, (uint32_t)u << 16);
}
// async global->LDS, 16B per lane; LDS dest = wave-uniform base + lane*16
__device__ __forceinline__ void gll16(void* lds, const void* g) {
  __builtin_amdgcn_global_load_lds(
      (const __attribute__((address_space(1))) void*)g,
      (__attribute__((address_space(3))) void*)lds, 16, 0, 0);
}

// ---------------------------------------------------------------------------
// One kernel converts x, w_attn, w_proj -> contiguous bf16 region.
// ---------------------------------------------------------------------------
__global__ __launch_bounds__(256) void cvt_all(const float* __restrict__ x,
                                               const float* __restrict__ wa,
                                               const float* __restrict__ wp,
                                               ushort* __restrict__ out) {
  static_assert(X4_ == 1048576 && WA4_ == 786432 && WP4_ == 262144, "sizes");
  static_assert((X4_ % 256) == 0 && ((X4_ + WA4_) % 256) == 0, "block-uniform");
  int i = blockIdx.x * 256 + threadIdx.x;      // 0 .. TOT4_-1
  const float* src; int off;
  if (i < X4_)              { src = x;  off = i; }
  else if (i < X4_ + WA4_)  { src = wa; off = i - X4_; }
  else                      { src = wp; off = i - (X4_ + WA4_); }
  float4 v = ((const float4*)src)[off];
  ushort4 o;
  o.x = f2bf(v.x); o.y = f2bf(v.y); o.z = f2bf(v.z); o.w = f2bf(v.w);
  ((ushort4*)out)[i] = o;
}

// ---------------------------------------------------------------------------
// bf16 MFMA GEMM (qkv), B^T weights: C[m][n] = sum_k A[m][k]*Bm[n][k].
// 128x128 tile, BK=64, 256 thr (2x2 waves, each 64x64 = 4x4 frags of 16x16).
// XCD 2D-patch swizzle. MODE 1 epilogue: q,k -> bf16 qkv; v -> vT[b][h][d][t].
// ---------------------------------------------------------------------------
template<int MODE>
__global__ __launch_bounds__(256) void gemm_mfma(
    const ushort* __restrict__ A, const ushort* __restrict__ Bm,
    void* __restrict__ Cout, ushort* __restrict__ vT,
    int M, int N, int K)
{
  __shared__ ushort As[128][64];
  __shared__ ushort Bs[128][64];
  const int tid  = threadIdx.x;
  const int lane = tid & 63, w = tid >> 6;
  const int wr = w >> 1, wc = w & 1;
  const int ll = lane & 15, lg = lane >> 4;
  const int r8 = lane >> 3;
  const int gc = ((lane & 7) ^ r8) << 3;   // swizzled global chunk offset (elems)
  const int lid = blockIdx.y * gridDim.x + blockIdx.x;
  const int j = lid & 7, g = lid >> 3;
  const int m0 = ((j & 3) * 8 + (g & 7)) * 128;
  const int n0 = ((j >> 2) * (N >> 8) + (g >> 3)) * 128;

  f32x4 acc[4][4] = {};

  for (int k0 = 0; k0 < K; k0 += 64) {
    __syncthreads();
#pragma unroll
    for (int iss = 0; iss < 4; ++iss) {
      int rb = w * 32 + iss * 8;           // wave-uniform LDS row base
      gll16(&As[rb][0], A  + (size_t)(m0 + rb + r8) * K + k0 + gc);
      gll16(&Bs[rb][0], Bm + (size_t)(n0 + rb + r8) * K + k0 + gc);
    }
    __syncthreads();                        // drains vmcnt+lgkmcnt
#pragma unroll
    for (int ks = 0; ks < 2; ++ks) {
      const int sw = ((ks * 4 + lg) ^ (ll & 7)) * 8;
      bf16x8 af[4], bfr[4];
#pragma unroll
      for (int mi = 0; mi < 4; ++mi)
        af[mi] = *(const bf16x8*)&As[wr * 64 + mi * 16 + ll][sw];
#pragma unroll
      for (int ni = 0; ni < 4; ++ni)
        bfr[ni] = *(const bf16x8*)&Bs[wc * 64 + ni * 16 + ll][sw];
#pragma unroll
      for (int mi = 0; mi < 4; ++mi)
#pragma unroll
        for (int ni = 0; ni < 4; ++ni)
          acc[mi][ni] = __builtin_amdgcn_mfma_f32_16x16x32_bf16(
              af[mi], bfr[ni], acc[mi][ni], 0, 0, 0);
    }
  }

  // C/D layout: col = lane&15, row = (lane>>4)*4 + reg
  const int mrow = wr * 64 + lg * 4;
  const int ncol = wc * 64 + ll;
  if (MODE == 0) {
    float* C = (float*)Cout;
#pragma unroll
    for (int mi = 0; mi < 4; ++mi)
#pragma unroll
      for (int ni = 0; ni < 4; ++ni)
#pragma unroll
        for (int r = 0; r < 4; ++r)
          C[(size_t)(m0 + mrow + mi * 16 + r) * N + n0 + ncol + ni * 16] =
              acc[mi][ni][r];
  } else {
    if (n0 < 2 * C_) {                      // q,k region -> bf16 qkv
      ushort* q = (ushort*)Cout;
#pragma unroll
      for (int mi = 0; mi < 4; ++mi)
#pragma unroll
        for (int ni = 0; ni < 4; ++ni)
#pragma unroll
          for (int r = 0; r < 4; ++r)
            q[(size_t)(m0 + mrow + mi * 16 + r) * F3_ + n0 + ncol + ni * 16] =
                f2bf(acc[mi][ni][r]);
    } else {                                // v region -> vT[b][h][d][t]
      const int bb = m0 >> 11;
      const int tb = (m0 & 2047) + mrow;
#pragma unroll
      for (int mi = 0; mi < 4; ++mi)
#pragma unroll
        for (int ni = 0; ni < 4; ++ni) {
          int f  = n0 + ncol + ni * 16 - 2 * C_;
          int hh = f >> 6, d = f & 63;
          ushort4 o;
          o.x = f2bf(acc[mi][ni][0]); o.y = f2bf(acc[mi][ni][1]);
          o.z = f2bf(acc[mi][ni][2]); o.w = f2bf(acc[mi][ni][3]);
          *(ushort4*)&vT[(((size_t)(bb * H_ + hh) * HD_ + d) << 11) + tb + mi * 16] = o;
        }
    }
  }
}

// ---------------------------------------------------------------------------
// Output-projection GEMM (R15-proven): out[m][n] = sum_k y[m][k]*wp[n][k].
// 64x128 tile, 4 waves split on N, grid 64x8 = 512 blocks -> 2 blocks/CU.
// ---------------------------------------------------------------------------
__global__ __launch_bounds__(256) void gemm_proj(
    const ushort* __restrict__ A, const ushort* __restrict__ Bm,
    float* __restrict__ C, int M, int N, int K)
{
  __shared__ ushort As[64][64];    // 8 KB
  __shared__ ushort Bs[128][64];   // 16 KB
  const int tid  = threadIdx.x;
  const int lane = tid & 63, w = tid >> 6;
  const int ll = lane & 15, lg = lane >> 4;
  const int r8 = lane >> 3;
  const int gc = ((lane & 7) ^ r8) << 3;
  const int m0 = blockIdx.x * 64, n0 = blockIdx.y * 128;

  f32x4 acc[4][2] = {};

  for (int k0 = 0; k0 < K; k0 += 64) {
    __syncthreads();
#pragma unroll
    for (int iss = 0; iss < 2; ++iss) {
      int rb = w * 16 + iss * 8;
      gll16(&As[rb][0], A + (size_t)(m0 + rb + r8) * K + k0 + gc);
    }
#pragma unroll
    for (int iss = 0; iss < 4; ++iss) {
      int rb = w * 32 + iss * 8;
      gll16(&Bs[rb][0], Bm + (size_t)(n0 + rb + r8) * K + k0 + gc);
    }
    __syncthreads();                        // drains vmcnt+lgkmcnt
#pragma unroll
    for (int ks = 0; ks < 2; ++ks) {
      const int sw = ((ks * 4 + lg) ^ (ll & 7)) * 8;
      bf16x8 af[4], bfr[2];
#pragma unroll
      for (int mi = 0; mi < 4; ++mi)
        af[mi] = *(const bf16x8*)&As[mi * 16 + ll][sw];        // broadcast rows
#pragma unroll
      for (int ni = 0; ni < 2; ++ni)
        bfr[ni] = *(const bf16x8*)&Bs[w * 32 + ni * 16 + ll][sw];
#pragma unroll
      for (int mi = 0; mi < 4; ++mi)
#pragma unroll
        for (int ni = 0; ni < 2; ++ni)
          acc[mi][ni] = __builtin_amdgcn_mfma_f32_16x16x32_bf16(
              af[mi], bfr[ni], acc[mi][ni], 0, 0, 0);
    }
  }

  // C/D layout: col = lane&15, row = (lane>>4)*4 + reg
#pragma unroll
  for (int mi = 0; mi < 4; ++mi)
#pragma unroll
    for (int ni = 0; ni < 2; ++ni)
#pragma unroll
      for (int r = 0; r < 4; ++r)
        C[(size_t)(m0 + mi * 16 + lg * 4 + r) * N + n0 + w * 32 + ni * 16 + ll] =
            acc[mi][ni][r];
}

// ---------------------------------------------------------------------------
// RoPE in-place on bf16 q,k. Folds 1/sqrt(HD)*log2(e) into q so attention
// softmax can use native exp2 (v_exp_f32) with no pre-multiply.
// ---------------------------------------------------------------------------
#define QSC 0.18033688f   // 0.125 * log2(e)
__global__ __launch_bounds__(256) void rope_bf(ushort* __restrict__ qkv,
                                               const float* __restrict__ fcos,
                                               const float* __restrict__ fsin) {
  int idx = blockIdx.x * 256 + threadIdx.x;   // B*T*H*16
  int i2 = idx & 15;
  int h  = (idx >> 4) & 15;
  int t  = (idx >> 8) & 2047;
  int b  = idx >> 19;
  int fi = t * 32 + i2 * 2;
  float c0 = fcos[fi], s0 = fsin[fi], c1 = fcos[fi + 1], s1 = fsin[fi + 1];
  size_t base = (size_t)(b * T_ + t) * F3_ + h * HD_ + i2 * 4;
  ushort4 qv = *(ushort4*)&qkv[base];
  ushort4 qo;
  { float e = bf2f(qv.x), o = bf2f(qv.y);
    qo.x = f2bf((e * c0 - o * s0) * QSC);
    qo.y = f2bf((e * s0 + o * c0) * QSC); }
  { float e = bf2f(qv.z), o = bf2f(qv.w);
    qo.z = f2bf((e * c1 - o * s1) * QSC);
    qo.w = f2bf((e * s1 + o * c1) * QSC); }
  *(ushort4*)&qkv[base] = qo;
  ushort4 kv = *(ushort4*)&qkv[base + C_];
  ushort4 ko;
  { float e = bf2f(kv.x), o = bf2f(kv.y);
    ko.x = f2bf(e * c0 - o * s0);
    ko.y = f2bf(e * s0 + o * c0); }
  { float e = bf2f(kv.z), o = bf2f(kv.w);
    ko.z = f2bf(e * c1 - o * s1);
    ko.w = f2bf(e * s1 + o * c1); }
  *(ushort4*)&qkv[base + C_] = ko;
}

// ---------------------------------------------------------------------------
// Flash attention (R7 base + R18 micro): bf16 MFMA, swapped-QK^T in-lane
// softmax (exp2 domain), dbuf K/V. 4 waves/block, 64 Q-rows, KV tiles 64.
// R18: (1) V fragments loaded into regs BEFORE softmax so the 8 ds_read_b128
// retire under the softmax VALU chain (they only depend on the tile-top
// barrier); (2) l_ kept as per-lane-copy partial, cross-copy reduction
// deferred to the epilogue (m_ is copy-uniform after the tmax shuffles).
// ---------------------------------------------------------------------------
__global__ __launch_bounds__(256) void attn_mfma(
    const ushort* __restrict__ qkv, const ushort* __restrict__ vT,
    ushort* __restrict__ y)
{
  __shared__ __align__(16) ushort Qs[64][64];
  __shared__ __align__(16) ushort Ks[2][64][64], VTs[2][64][64];
  __shared__ __align__(16) ushort Ps[4][16][72];

  const int qt = 31 - blockIdx.y;        // heavy tiles first
  const int bh = blockIdx.x;
  const int b = bh >> 4, h = bh & 15;
  const int q0 = qt * 64;
  const int tid = threadIdx.x, lane = tid & 63, w = tid >> 6;
  const int ll = lane & 15, lg = lane >> 4;
  const int r8 = lane >> 3;
  const int gc = ((lane & 7) ^ r8) << 3;
  const float NEG = -3.0e38f;

  const ushort* qb = qkv + (size_t)(b * T_) * F3_ + h * HD_;
  const ushort* kb = qb + C_;
  const ushort* vb = vT + ((size_t)(b * H_ + h) * HD_ << 11);

  // prologue: stage Q and K/V tile 0 into buf 0
#pragma unroll
  for (int iss = 0; iss < 2; ++iss) {
    int rb = w * 16 + iss * 8;
    gll16(&Qs[rb][0], qb + (size_t)(q0 + rb + r8) * F3_ + gc);
    gll16(&Ks[0][rb][0],  kb + (size_t)(rb + r8) * F3_ + gc);
    gll16(&VTs[0][rb][0], vb + ((size_t)(rb + r8) << 11) + gc);
  }
  __syncthreads();

  bf16x8 qf[2];
#pragma unroll
  for (int ks = 0; ks < 2; ++ks)
    qf[ks] = *(const bf16x8*)&Qs[w * 16 + ll][((ks * 4 + lg) ^ (ll & 7)) * 8];

  f32x4 oacc[4] = {};
  float m_ = NEG, l_ = 0.f;
  int cur = 0;

  for (int kt = 0; kt <= qt; ++kt) {
    // issue next tile's async loads (overlap with this tile's compute)
    if (kt < qt) {
#pragma unroll
      for (int iss = 0; iss < 2; ++iss) {
        int rb = w * 16 + iss * 8;
        gll16(&Ks[cur ^ 1][rb][0],
              kb + (size_t)((kt + 1) * 64 + rb + r8) * F3_ + gc);
        gll16(&VTs[cur ^ 1][rb][0],
              vb + ((size_t)(rb + r8) << 11) + (kt + 1) * 64 + gc);
      }
    }

    // ---- S^T = K Q^T ----
    f32x4 sacc[4] = {};
#pragma unroll
    for (int ks = 0; ks < 2; ++ks) {
      const int sw = ((ks * 4 + lg) ^ (ll & 7)) * 8;
      bf16x8 kf[4];
#pragma unroll
      for (int j = 0; j < 4; ++j)
        kf[j] = *(const bf16x8*)&Ks[cur][j * 16 + ll][sw];
      __builtin_amdgcn_s_setprio(1);
#pragma unroll
      for (int j = 0; j < 4; ++j)
        sacc[j] = __builtin_amdgcn_mfma_f32_16x16x32_bf16(kf[j], qf[ks], sacc[j], 0, 0, 0);
      __builtin_amdgcn_s_setprio(0);
    }

    if (kt == qt) {                       // causal mask on diagonal tile
#pragma unroll
      for (int j = 0; j < 4; ++j)
#pragma unroll
        for (int r = 0; r < 4; ++r)
          if (j * 16 + lg * 4 + r > w * 16 + ll) sacc[j][r] = NEG;
    }

    // ---- EARLY V loads: issue ds_reads now; they retire under softmax ----
    bf16x8 vf[2][4];
#pragma unroll
    for (int ks = 0; ks < 2; ++ks) {
      const int sw = ((ks * 4 + lg) ^ (ll & 7)) * 8;
#pragma unroll
      for (int dj = 0; dj < 4; ++dj)
        vf[ks][dj] = *(const bf16x8*)&VTs[cur][dj * 16 + ll][sw];
    }

    // ---- in-lane online softmax, exp2 domain (row = ll) ----
    float tmax;
    {
      float t0 = fmaxf(fmaxf(sacc[0][0], sacc[0][1]), fmaxf(sacc[0][2], sacc[0][3]));
      float t1 = fmaxf(fmaxf(sacc[1][0], sacc[1][1]), fmaxf(sacc[1][2], sacc[1][3]));
      float t2 = fmaxf(fmaxf(sacc[2][0], sacc[2][1]), fmaxf(sacc[2][2], sacc[2][3]));
      float t3 = fmaxf(fmaxf(sacc[3][0], sacc[3][1]), fmaxf(sacc[3][2], sacc[3][3]));
      tmax = fmaxf(fmaxf(t0, t1), fmaxf(t2, t3));
      tmax = fmaxf(tmax, __shfl_xor(tmax, 16));
      tmax = fmaxf(tmax, __shfl_xor(tmax, 32));
    }
    if (!__all(tmax <= m_ + 11.5441f)) {  // defer-max (8 nats in log2 units)
      float mnew = fmaxf(m_, tmax);
      float al = __builtin_amdgcn_exp2f(m_ - mnew);   // 0 on first tile
      l_ *= al;                            // per-copy partial, uniform scale
      m_ = mnew;
#pragma unroll
      for (int r = 0; r < 4; ++r) {
        float alr = __shfl(al, lg * 4 + r);
#pragma unroll
        for (int dj = 0; dj < 4; ++dj) oacc[dj][r] *= alr;
      }
    }
#pragma unroll
    for (int j = 0; j < 4; ++j) {
      float p0 = __builtin_amdgcn_exp2f(sacc[j][0] - m_);
      float p1 = __builtin_amdgcn_exp2f(sacc[j][1] - m_);
      float p2 = __builtin_amdgcn_exp2f(sacc[j][2] - m_);
      float p3 = __builtin_amdgcn_exp2f(sacc[j][3] - m_);
      l_ += (p0 + p1) + (p2 + p3);        // per-copy partial (16 keys/copy)
      // truncating bf16 pack (probabilities: RNE not needed)
      uint u0 = __builtin_bit_cast(uint32_t, p0) >> 16;
      uint u1 = __builtin_bit_cast(uint32_t, p1) & 0xffff0000u;
      uint u2 = __builtin_bit_cast(uint32_t, p2) >> 16;
      uint u3 = __builtin_bit_cast(uint32_t, p3) & 0xffff0000u;
      uint2 pk = make_uint2(u0 | u1, u2 | u3);
      *(uint2*)&Ps[w][ll][j * 16 + lg * 4] = pk;
    }

    // ---- O += P V (V already in regs) ----
#pragma unroll
    for (int ks = 0; ks < 2; ++ks) {
      bf16x8 pf = *(const bf16x8*)&Ps[w][ll][ks * 32 + lg * 8];
      __builtin_amdgcn_s_setprio(1);
#pragma unroll
      for (int dj = 0; dj < 4; ++dj)
        oacc[dj] = __builtin_amdgcn_mfma_f32_16x16x32_bf16(pf, vf[ks][dj], oacc[dj], 0, 0, 0);
      __builtin_amdgcn_s_setprio(0);
    }

    __syncthreads();   // all waves done with buf[cur]; next buf staged
    cur ^= 1;
  }

  // epilogue: reduce l_ across the 4 lane-copies, then normalize + store
  l_ += __shfl_xor(l_, 16);
  l_ += __shfl_xor(l_, 32);
#pragma unroll
  for (int r = 0; r < 4; ++r) {
    float lr = __shfl(l_, lg * 4 + r);
    float inv = 1.0f / lr;
    int row = q0 + w * 16 + lg * 4 + r;
#pragma unroll
    for (int dj = 0; dj < 4; ++dj)
      y[(size_t)(b * T_ + row) * C_ + h * HD_ + dj * 16 + ll] =
          f2bf(oacc[dj][r] * inv);
  }
}

// ---------------------------------------------------------------------------
extern "C" void kernel_launch(void* const* d_in, const int* in_sizes, int n_in,
                              void* d_out, int out_size, void* d_ws, size_t ws_size,
                              hipStream_t stream) {
  const float* x      = (const float*)d_in[0];
  const float* w_attn = (const float*)d_in[1];
  const float* w_proj = (const float*)d_in[2];
  const float* fcos   = (const float*)d_in[3];
  const float* fsin   = (const float*)d_in[4];
  float* out = (float*)d_out;

  ushort* xb   = (ushort*)d_ws;                 // 4096x1024 bf16
  ushort* wab  = xb   + (size_t)4096 * 1024;    // 3072x1024
  ushort* wpb  = wab  + (size_t)3072 * 1024;    // 1024x1024
  ushort* qkvb = wpb  + (size_t)1024 * 1024;    // 4096x3072 (q,k only)
  ushort* vt   = qkvb + (size_t)4096 * 3072;    // [2][16][64][2048]
  ushort* yb   = vt   + (size_t)32 * 64 * 2048; // 4096x1024

  cvt_all<<<TOT4_ / 256, 256, 0, stream>>>(x, w_attn, w_proj, xb);

  { dim3 g(32, 24); gemm_mfma<1><<<g, 256, 0, stream>>>(xb, wab, qkvb, vt, 4096, F3_, C_); }
  rope_bf<<<4096, 256, 0, stream>>>(qkvb, fcos, fsin);
  { dim3 g(32, 32); attn_mfma<<<g, 256, 0, stream>>>(qkvb, vt, yb); }
  { dim3 g(64, 8);  gemm_proj<<<g, 256, 0, stream>>>(yb, wpb, out, 4096, C_, C_); }
}

// Round 19
// 106.273 us; speedup vs baseline: 1.0757x; 1.0027x over previous
//
#include <hip/hip_runtime.h>
#include <math.h>

#define B_  2
#define T_  2048
#define C_  1024
#define H_  16
#define HD_ 64
#define F3_ 3072   // 3*C

// float4 unit counts for cvt_all (derived, not hand-copied):
#define X4_   ((B_ * T_ * C_) / 4)         // 2*2048*1024/4 = 1,048,576
#define WA4_  ((F3_ * C_) / 4)             // 3072*1024/4   =   786,432
#define WP4_  ((C_ * C_) / 4)              // 1024*1024/4   =   262,144
#define TOT4_ (X4_ + WA4_ + WP4_)          //               = 2,097,152 = 8192*256

typedef __attribute__((ext_vector_type(8))) __bf16 bf16x8;
typedef __attribute__((ext_vector_type(4))) float  f32x4;

__device__ __forceinline__ ushort f2bf(float f) {
  uint32_t u = __builtin_bit_cast(uint32_t, f);
  u += 0x7fff + ((u >> 16) & 1);        // RNE
  return (ushort)(u >> 16);
}
__device__ __forceinline__ float bf2f(ushort u) {
  return __builtin_bit_cast(float, (uint32_t)u << 16);
}
// async global->LDS, 16B per lane; LDS dest = wave-uniform base + lane*16
__device__ __forceinline__ void gll16(void* lds, const void* g) {
  __builtin_amdgcn_global_load_lds(
      (const __attribute__((address_space(1))) void*)g,
      (__attribute__((address_space(3))) void*)lds, 16, 0, 0);
}

// ---------------------------------------------------------------------------
// One kernel converts x, w_attn, w_proj -> contiguous bf16 region.
// ---------------------------------------------------------------------------
__global__ __launch_bounds__(256) void cvt_all(const float* __restrict__ x,
                                               const float* __restrict__ wa,
                                               const float* __restrict__ wp,
                                               ushort* __restrict__ out) {
  static_assert(X4_ == 1048576 && WA4_ == 786432 && WP4_ == 262144, "sizes");
  static_assert((X4_ % 256) == 0 && ((X4_ + WA4_) % 256) == 0, "block-uniform");
  int i = blockIdx.x * 256 + threadIdx.x;      // 0 .. TOT4_-1
  const float* src; int off;
  if (i < X4_)              { src = x;  off = i; }
  else if (i < X4_ + WA4_)  { src = wa; off = i - X4_; }
  else                      { src = wp; off = i - (X4_ + WA4_); }
  float4 v = ((const float4*)src)[off];
  ushort4 o;
  o.x = f2bf(v.x); o.y = f2bf(v.y); o.z = f2bf(v.z); o.w = f2bf(v.w);
  ((ushort4*)out)[i] = o;
}

// ---------------------------------------------------------------------------
// bf16 MFMA GEMM (qkv), B^T weights: C[m][n] = sum_k A[m][k]*Bm[n][k].
// 128x128 tile, BK=64, 256 thr (2x2 waves, each 64x64 = 4x4 frags of 16x16).
// XCD 2D-patch swizzle. MODE 1 epilogue: q,k -> bf16 qkv; v -> vT[b][h][d][t].
// ---------------------------------------------------------------------------
template<int MODE>
__global__ __launch_bounds__(256) void gemm_mfma(
    const ushort* __restrict__ A, const ushort* __restrict__ Bm,
    void* __restrict__ Cout, ushort* __restrict__ vT,
    int M, int N, int K)
{
  __shared__ ushort As[128][64];
  __shared__ ushort Bs[128][64];
  const int tid  = threadIdx.x;
  const int lane = tid & 63, w = tid >> 6;
  const int wr = w >> 1, wc = w & 1;
  const int ll = lane & 15, lg = lane >> 4;
  const int r8 = lane >> 3;
  const int gc = ((lane & 7) ^ r8) << 3;   // swizzled global chunk offset (elems)
  const int lid = blockIdx.y * gridDim.x + blockIdx.x;
  const int j = lid & 7, g = lid >> 3;
  const int m0 = ((j & 3) * 8 + (g & 7)) * 128;
  const int n0 = ((j >> 2) * (N >> 8) + (g >> 3)) * 128;

  f32x4 acc[4][4] = {};

  for (int k0 = 0; k0 < K; k0 += 64) {
    __syncthreads();
#pragma unroll
    for (int iss = 0; iss < 4; ++iss) {
      int rb = w * 32 + iss * 8;           // wave-uniform LDS row base
      gll16(&As[rb][0], A  + (size_t)(m0 + rb + r8) * K + k0 + gc);
      gll16(&Bs[rb][0], Bm + (size_t)(n0 + rb + r8) * K + k0 + gc);
    }
    __syncthreads();                        // drains vmcnt+lgkmcnt
#pragma unroll
    for (int ks = 0; ks < 2; ++ks) {
      const int sw = ((ks * 4 + lg) ^ (ll & 7)) * 8;
      bf16x8 af[4], bfr[4];
#pragma unroll
      for (int mi = 0; mi < 4; ++mi)
        af[mi] = *(const bf16x8*)&As[wr * 64 + mi * 16 + ll][sw];
#pragma unroll
      for (int ni = 0; ni < 4; ++ni)
        bfr[ni] = *(const bf16x8*)&Bs[wc * 64 + ni * 16 + ll][sw];
#pragma unroll
      for (int mi = 0; mi < 4; ++mi)
#pragma unroll
        for (int ni = 0; ni < 4; ++ni)
          acc[mi][ni] = __builtin_amdgcn_mfma_f32_16x16x32_bf16(
              af[mi], bfr[ni], acc[mi][ni], 0, 0, 0);
    }
  }

  // C/D layout: col = lane&15, row = (lane>>4)*4 + reg
  const int mrow = wr * 64 + lg * 4;
  const int ncol = wc * 64 + ll;
  if (MODE == 0) {
    float* C = (float*)Cout;
#pragma unroll
    for (int mi = 0; mi < 4; ++mi)
#pragma unroll
      for (int ni = 0; ni < 4; ++ni)
#pragma unroll
        for (int r = 0; r < 4; ++r)
          C[(size_t)(m0 + mrow + mi * 16 + r) * N + n0 + ncol + ni * 16] =
              acc[mi][ni][r];
  } else {
    if (n0 < 2 * C_) {                      // q,k region -> bf16 qkv
      ushort* q = (ushort*)Cout;
#pragma unroll
      for (int mi = 0; mi < 4; ++mi)
#pragma unroll
        for (int ni = 0; ni < 4; ++ni)
#pragma unroll
          for (int r = 0; r < 4; ++r)
            q[(size_t)(m0 + mrow + mi * 16 + r) * F3_ + n0 + ncol + ni * 16] =
                f2bf(acc[mi][ni][r]);
    } else {                                // v region -> vT[b][h][d][t]
      const int bb = m0 >> 11;
      const int tb = (m0 & 2047) + mrow;
#pragma unroll
      for (int mi = 0; mi < 4; ++mi)
#pragma unroll
        for (int ni = 0; ni < 4; ++ni) {
          int f  = n0 + ncol + ni * 16 - 2 * C_;
          int hh = f >> 6, d = f & 63;
          ushort4 o;
          o.x = f2bf(acc[mi][ni][0]); o.y = f2bf(acc[mi][ni][1]);
          o.z = f2bf(acc[mi][ni][2]); o.w = f2bf(acc[mi][ni][3]);
          *(ushort4*)&vT[(((size_t)(bb * H_ + hh) * HD_ + d) << 11) + tb + mi * 16] = o;
        }
    }
  }
}

// ---------------------------------------------------------------------------
// Output-projection GEMM (R15-proven): out[m][n] = sum_k y[m][k]*wp[n][k].
// 64x128 tile, 4 waves split on N, grid 64x8 = 512 blocks -> 2 blocks/CU.
// ---------------------------------------------------------------------------
__global__ __launch_bounds__(256) void gemm_proj(
    const ushort* __restrict__ A, const ushort* __restrict__ Bm,
    float* __restrict__ C, int M, int N, int K)
{
  __shared__ ushort As[64][64];    // 8 KB
  __shared__ ushort Bs[128][64];   // 16 KB
  const int tid  = threadIdx.x;
  const int lane = tid & 63, w = tid >> 6;
  const int ll = lane & 15, lg = lane >> 4;
  const int r8 = lane >> 3;
  const int gc = ((lane & 7) ^ r8) << 3;
  const int m0 = blockIdx.x * 64, n0 = blockIdx.y * 128;

  f32x4 acc[4][2] = {};

  for (int k0 = 0; k0 < K; k0 += 64) {
    __syncthreads();
#pragma unroll
    for (int iss = 0; iss < 2; ++iss) {
      int rb = w * 16 + iss * 8;
      gll16(&As[rb][0], A + (size_t)(m0 + rb + r8) * K + k0 + gc);
    }
#pragma unroll
    for (int iss = 0; iss < 4; ++iss) {
      int rb = w * 32 + iss * 8;
      gll16(&Bs[rb][0], Bm + (size_t)(n0 + rb + r8) * K + k0 + gc);
    }
    __syncthreads();                        // drains vmcnt+lgkmcnt
#pragma unroll
    for (int ks = 0; ks < 2; ++ks) {
      const int sw = ((ks * 4 + lg) ^ (ll & 7)) * 8;
      bf16x8 af[4], bfr[2];
#pragma unroll
      for (int mi = 0; mi < 4; ++mi)
        af[mi] = *(const bf16x8*)&As[mi * 16 + ll][sw];        // broadcast rows
#pragma unroll
      for (int ni = 0; ni < 2; ++ni)
        bfr[ni] = *(const bf16x8*)&Bs[w * 32 + ni * 16 + ll][sw];
#pragma unroll
      for (int mi = 0; mi < 4; ++mi)
#pragma unroll
        for (int ni = 0; ni < 2; ++ni)
          acc[mi][ni] = __builtin_amdgcn_mfma_f32_16x16x32_bf16(
              af[mi], bfr[ni], acc[mi][ni], 0, 0, 0);
    }
  }

  // C/D layout: col = lane&15, row = (lane>>4)*4 + reg
#pragma unroll
  for (int mi = 0; mi < 4; ++mi)
#pragma unroll
    for (int ni = 0; ni < 2; ++ni)
#pragma unroll
      for (int r = 0; r < 4; ++r)
        C[(size_t)(m0 + mi * 16 + lg * 4 + r) * N + n0 + w * 32 + ni * 16 + ll] =
            acc[mi][ni][r];
}

// ---------------------------------------------------------------------------
// RoPE in-place on bf16 q,k. Folds 1/sqrt(HD)*log2(e) into q so attention
// softmax can use native exp2 (v_exp_f32) with no pre-multiply.
// ---------------------------------------------------------------------------
#define QSC 0.18033688f   // 0.125 * log2(e)
__global__ __launch_bounds__(256) void rope_bf(ushort* __restrict__ qkv,
                                               const float* __restrict__ fcos,
                                               const float* __restrict__ fsin) {
  int idx = blockIdx.x * 256 + threadIdx.x;   // B*T*H*16
  int i2 = idx & 15;
  int h  = (idx >> 4) & 15;
  int t  = (idx >> 8) & 2047;
  int b  = idx >> 19;
  int fi = t * 32 + i2 * 2;
  float c0 = fcos[fi], s0 = fsin[fi], c1 = fcos[fi + 1], s1 = fsin[fi + 1];
  size_t base = (size_t)(b * T_ + t) * F3_ + h * HD_ + i2 * 4;
  ushort4 qv = *(ushort4*)&qkv[base];
  ushort4 qo;
  { float e = bf2f(qv.x), o = bf2f(qv.y);
    qo.x = f2bf((e * c0 - o * s0) * QSC);
    qo.y = f2bf((e * s0 + o * c0) * QSC); }
  { float e = bf2f(qv.z), o = bf2f(qv.w);
    qo.z = f2bf((e * c1 - o * s1) * QSC);
    qo.w = f2bf((e * s1 + o * c1) * QSC); }
  *(ushort4*)&qkv[base] = qo;
  ushort4 kv = *(ushort4*)&qkv[base + C_];
  ushort4 ko;
  { float e = bf2f(kv.x), o = bf2f(kv.y);
    ko.x = f2bf(e * c0 - o * s0);
    ko.y = f2bf(e * s0 + o * c0); }
  { float e = bf2f(kv.z), o = bf2f(kv.w);
    ko.z = f2bf(e * c1 - o * s1);
    ko.w = f2bf(e * s1 + o * c1); }
  *(ushort4*)&qkv[base + C_] = ko;
}

// ---------------------------------------------------------------------------
// Flash attention (R18 base + R19 micro): bf16 MFMA, swapped-QK^T in-lane
// softmax (exp2 domain), dbuf K/V. 4 waves/block, 64 Q-rows, KV tiles 64.
// R18: early V loads (retire under softmax); deferred l_ reduction.
// R19: (1) all 8 K-fragment ds_reads batched before the QK^T MFMA cluster
// (ks=1 reads retire under ks=0 MFMAs); (2) wave-uniform skip of exact-zero
// MFMAs on the diagonal tile: QK^T j-block skipped when j > w (mask
// overwrites every element anyway); PV ks=1 skipped for w < 2 (all P in
// keys 32..63 masked -> exp=0 -> zero contribution). No divergence: j, ks
// are compile-time; w is wave-uniform.
// ---------------------------------------------------------------------------
__global__ __launch_bounds__(256) void attn_mfma(
    const ushort* __restrict__ qkv, const ushort* __restrict__ vT,
    ushort* __restrict__ y)
{
  __shared__ __align__(16) ushort Qs[64][64];
  __shared__ __align__(16) ushort Ks[2][64][64], VTs[2][64][64];
  __shared__ __align__(16) ushort Ps[4][16][72];

  const int qt = 31 - blockIdx.y;        // heavy tiles first
  const int bh = blockIdx.x;
  const int b = bh >> 4, h = bh & 15;
  const int q0 = qt * 64;
  const int tid = threadIdx.x, lane = tid & 63, w = tid >> 6;
  const int ll = lane & 15, lg = lane >> 4;
  const int r8 = lane >> 3;
  const int gc = ((lane & 7) ^ r8) << 3;
  const float NEG = -3.0e38f;

  const ushort* qb = qkv + (size_t)(b * T_) * F3_ + h * HD_;
  const ushort* kb = qb + C_;
  const ushort* vb = vT + ((size_t)(b * H_ + h) * HD_ << 11);

  // prologue: stage Q and K/V tile 0 into buf 0
#pragma unroll
  for (int iss = 0; iss < 2; ++iss) {
    int rb = w * 16 + iss * 8;
    gll16(&Qs[rb][0], qb + (size_t)(q0 + rb + r8) * F3_ + gc);
    gll16(&Ks[0][rb][0],  kb + (size_t)(rb + r8) * F3_ + gc);
    gll16(&VTs[0][rb][0], vb + ((size_t)(rb + r8) << 11) + gc);
  }
  __syncthreads();

  bf16x8 qf[2];
#pragma unroll
  for (int ks = 0; ks < 2; ++ks)
    qf[ks] = *(const bf16x8*)&Qs[w * 16 + ll][((ks * 4 + lg) ^ (ll & 7)) * 8];

  f32x4 oacc[4] = {};
  float m_ = NEG, l_ = 0.f;
  int cur = 0;

  for (int kt = 0; kt <= qt; ++kt) {
    const bool diag = (kt == qt);
    // issue next tile's async loads (overlap with this tile's compute)
    if (kt < qt) {
#pragma unroll
      for (int iss = 0; iss < 2; ++iss) {
        int rb = w * 16 + iss * 8;
        gll16(&Ks[cur ^ 1][rb][0],
              kb + (size_t)((kt + 1) * 64 + rb + r8) * F3_ + gc);
        gll16(&VTs[cur ^ 1][rb][0],
              vb + ((size_t)(rb + r8) << 11) + (kt + 1) * 64 + gc);
      }
    }

    // ---- S^T = K Q^T : batch all 8 kf reads, then the MFMA cluster ----
    f32x4 sacc[4] = {};
    bf16x8 kf[2][4];
#pragma unroll
    for (int ks = 0; ks < 2; ++ks) {
      const int sw = ((ks * 4 + lg) ^ (ll & 7)) * 8;
#pragma unroll
      for (int j = 0; j < 4; ++j)
        kf[ks][j] = *(const bf16x8*)&Ks[cur][j * 16 + ll][sw];
    }
    __builtin_amdgcn_s_setprio(1);
#pragma unroll
    for (int ks = 0; ks < 2; ++ks)
#pragma unroll
      for (int j = 0; j < 4; ++j)
        if (!diag || j <= w)              // wave-uniform; masked blocks exact-skip
          sacc[j] = __builtin_amdgcn_mfma_f32_16x16x32_bf16(kf[ks][j], qf[ks], sacc[j], 0, 0, 0);
    __builtin_amdgcn_s_setprio(0);

    if (diag) {                           // causal mask on diagonal tile
#pragma unroll
      for (int j = 0; j < 4; ++j)
#pragma unroll
        for (int r = 0; r < 4; ++r)
          if (j * 16 + lg * 4 + r > w * 16 + ll) sacc[j][r] = NEG;
    }

    // ---- EARLY V loads: issue ds_reads now; they retire under softmax ----
    bf16x8 vf[2][4];
#pragma unroll
    for (int ks = 0; ks < 2; ++ks) {
      const int sw = ((ks * 4 + lg) ^ (ll & 7)) * 8;
#pragma unroll
      for (int dj = 0; dj < 4; ++dj)
        vf[ks][dj] = *(const bf16x8*)&VTs[cur][dj * 16 + ll][sw];
    }

    // ---- in-lane online softmax, exp2 domain (row = ll) ----
    float tmax;
    {
      float t0 = fmaxf(fmaxf(sacc[0][0], sacc[0][1]), fmaxf(sacc[0][2], sacc[0][3]));
      float t1 = fmaxf(fmaxf(sacc[1][0], sacc[1][1]), fmaxf(sacc[1][2], sacc[1][3]));
      float t2 = fmaxf(fmaxf(sacc[2][0], sacc[2][1]), fmaxf(sacc[2][2], sacc[2][3]));
      float t3 = fmaxf(fmaxf(sacc[3][0], sacc[3][1]), fmaxf(sacc[3][2], sacc[3][3]));
      tmax = fmaxf(fmaxf(t0, t1), fmaxf(t2, t3));
      tmax = fmaxf(tmax, __shfl_xor(tmax, 16));
      tmax = fmaxf(tmax, __shfl_xor(tmax, 32));
    }
    if (!__all(tmax <= m_ + 11.5441f)) {  // defer-max (8 nats in log2 units)
      float mnew = fmaxf(m_, tmax);
      float al = __builtin_amdgcn_exp2f(m_ - mnew);   // 0 on first tile
      l_ *= al;                            // per-copy partial, uniform scale
      m_ = mnew;
#pragma unroll
      for (int r = 0; r < 4; ++r) {
        float alr = __shfl(al, lg * 4 + r);
#pragma unroll
        for (int dj = 0; dj < 4; ++dj) oacc[dj][r] *= alr;
      }
    }
#pragma unroll
    for (int j = 0; j < 4; ++j) {
      float p0 = __builtin_amdgcn_exp2f(sacc[j][0] - m_);
      float p1 = __builtin_amdgcn_exp2f(sacc[j][1] - m_);
      float p2 = __builtin_amdgcn_exp2f(sacc[j][2] - m_);
      float p3 = __builtin_amdgcn_exp2f(sacc[j][3] - m_);
      l_ += (p0 + p1) + (p2 + p3);        // per-copy partial (16 keys/copy)
      // truncating bf16 pack (probabilities: RNE not needed)
      uint u0 = __builtin_bit_cast(uint32_t, p0) >> 16;
      uint u1 = __builtin_bit_cast(uint32_t, p1) & 0xffff0000u;
      uint u2 = __builtin_bit_cast(uint32_t, p2) >> 16;
      uint u3 = __builtin_bit_cast(uint32_t, p3) & 0xffff0000u;
      uint2 pk = make_uint2(u0 | u1, u2 | u3);
      *(uint2*)&Ps[w][ll][j * 16 + lg * 4] = pk;
    }

    // ---- O += P V (V already in regs) ----
#pragma unroll
    for (int ks = 0; ks < 2; ++ks) {
      if (diag && ks == 1 && w < 2) continue;  // all P in keys 32..63 are 0
      bf16x8 pf = *(const bf16x8*)&Ps[w][ll][ks * 32 + lg * 8];
      __builtin_amdgcn_s_setprio(1);
#pragma unroll
      for (int dj = 0; dj < 4; ++dj)
        oacc[dj] = __builtin_amdgcn_mfma_f32_16x16x32_bf16(pf, vf[ks][dj], oacc[dj], 0, 0, 0);
      __builtin_amdgcn_s_setprio(0);
    }

    __syncthreads();   // all waves done with buf[cur]; next buf staged
    cur ^= 1;
  }

  // epilogue: reduce l_ across the 4 lane-copies, then normalize + store
  l_ += __shfl_xor(l_, 16);
  l_ += __shfl_xor(l_, 32);
#pragma unroll
  for (int r = 0; r < 4; ++r) {
    float lr = __shfl(l_, lg * 4 + r);
    float inv = 1.0f / lr;
    int row = q0 + w * 16 + lg * 4 + r;
#pragma unroll
    for (int dj = 0; dj < 4; ++dj)
      y[(size_t)(b * T_ + row) * C_ + h * HD_ + dj * 16 + ll] =
          f2bf(oacc[dj][r] * inv);
  }
}

// ---------------------------------------------------------------------------
extern "C" void kernel_launch(void* const* d_in, const int* in_sizes, int n_in,
                              void* d_out, int out_size, void* d_ws, size_t ws_size,
                              hipStream_t stream) {
  const float* x      = (const float*)d_in[0];
  const float* w_attn = (const float*)d_in[1];
  const float* w_proj = (const float*)d_in[2];
  const float* fcos   = (const float*)d_in[3];
  const float* fsin   = (const float*)d_in[4];
  float* out = (float*)d_out;

  ushort* xb   = (ushort*)d_ws;                 // 4096x1024 bf16
  ushort* wab  = xb   + (size_t)4096 * 1024;    // 3072x1024
  ushort* wpb  = wab  + (size_t)3072 * 1024;    // 1024x1024
  ushort* qkvb = wpb  + (size_t)1024 * 1024;    // 4096x3072 (q,k only)
  ushort* vt   = qkvb + (size_t)4096 * 3072;    // [2][16][64][2048]
  ushort* yb   = vt   + (size_t)32 * 64 * 2048; // 4096x1024

  cvt_all<<<TOT4_ / 256, 256, 0, stream>>>(x, w_attn, w_proj, xb);

  { dim3 g(32, 24); gemm_mfma<1><<<g, 256, 0, stream>>>(xb, wab, qkvb, vt, 4096, F3_, C_); }
  rope_bf<<<4096, 256, 0, stream>>>(qkvb, fcos, fsin);
  { dim3 g(32, 32); attn_mfma<<<g, 256, 0, stream>>>(qkvb, vt, yb); }
  { dim3 g(64, 8);  gemm_proj<<<g, 256, 0, stream>>>(yb, wpb, out, 4096, C_, C_); }
}